// Round 1
// baseline (312.774 us; speedup 1.0000x reference)
//
#include <hip/hip_runtime.h>
#include <hip/hip_bf16.h>

typedef __attribute__((ext_vector_type(8))) short short8;
typedef __attribute__((ext_vector_type(4))) float f32x4;

#define DEV __device__ __forceinline__

DEV float bf2f(unsigned short u) {
    union { unsigned int i; float f; } v;
    v.i = ((unsigned int)u) << 16;
    return v.f;
}
DEV unsigned short f2bf(float f) {
    union { float f; unsigned int i; } v; v.f = f;
    unsigned int r = v.i + 0x7FFFu + ((v.i >> 16) & 1u);
    return (unsigned short)(r >> 16);
}
DEV float sigmoidf_(float x) {
    return 1.0f / (1.0f + __expf(-x));
}

// ---------------------------------------------------------------------------
// 1. fp32 -> bf16 conversion for x and h (8 elems/thread, fully coalesced)
// ---------------------------------------------------------------------------
__global__ void conv_xh(const float* __restrict__ x, const float* __restrict__ h,
                        unsigned short* __restrict__ xw, unsigned short* __restrict__ hw,
                        int n)
{
    int i = (blockIdx.x * blockDim.x + threadIdx.x) * 8;
    const float* src; unsigned short* dst; int off;
    if (i < n) { src = x; dst = xw; off = i; }
    else       { src = h; dst = hw; off = i - n; }
    float4 a = *(const float4*)(src + off);
    float4 b = *(const float4*)(src + off + 4);
    union { uint4 v; unsigned short s[8]; } o;
    o.s[0]=f2bf(a.x); o.s[1]=f2bf(a.y); o.s[2]=f2bf(a.z); o.s[3]=f2bf(a.w);
    o.s[4]=f2bf(b.x); o.s[5]=f2bf(b.y); o.s[6]=f2bf(b.z); o.s[7]=f2bf(b.w);
    *(uint4*)(dst + off) = o.v;
}

// ---------------------------------------------------------------------------
// 2. transpose + convert the six 1024x1024 f32 weights into bf16 B^T layout
//    dst[n][k] = src[k][n].  blockIdx.z selects the matrix.
// ---------------------------------------------------------------------------
__global__ void tconv(const float* __restrict__ s0, const float* __restrict__ s1,
                      const float* __restrict__ s2, const float* __restrict__ s3,
                      const float* __restrict__ s4, const float* __restrict__ s5,
                      unsigned short* __restrict__ d0, unsigned short* __restrict__ d1,
                      unsigned short* __restrict__ d2, unsigned short* __restrict__ d3,
                      unsigned short* __restrict__ d4, unsigned short* __restrict__ d5)
{
    __shared__ float lds[32][33];           // +1 pad: conflict-free transpose
    const float* src; unsigned short* dst;
    switch (blockIdx.z) {
        case 0: src=s0; dst=d0; break;
        case 1: src=s1; dst=d1; break;
        case 2: src=s2; dst=d2; break;
        case 3: src=s3; dst=d3; break;
        case 4: src=s4; dst=d4; break;
        default: src=s5; dst=d5; break;
    }
    int k0 = blockIdx.x * 32, n0 = blockIdx.y * 32;
    int tx = threadIdx.x & 31, ty = threadIdx.x >> 5;   // 32 x 8
    #pragma unroll
    for (int i = 0; i < 4; i++)
        lds[ty + 8*i][tx] = src[(size_t)(k0 + ty + 8*i)*1024 + n0 + tx];
    __syncthreads();
    #pragma unroll
    for (int i = 0; i < 4; i++)
        dst[(size_t)(n0 + ty + 8*i)*1024 + k0 + tx] = f2bf(lds[tx][ty + 8*i]);
}

// ---------------------------------------------------------------------------
// 3. bf16 GEMM, m97 structure: 128x128 tile, BK=32, 4 waves (2x2),
//    each wave 64x64 = 4x4 fragments of 16x16x32 MFMA.
//    A: [M][K] bf16 row-major, Bt: [N][K] bf16 (B transposed).
//    EPI==0: C written as bf16 [M][N].
//    EPI==1: fused GRU epilogue -> n = sigmoid(acc + xn + bn),
//            out = (1-z)*h + z*n  (f32, direct to d_out).
// ---------------------------------------------------------------------------
template<int EPI>
__global__ __launch_bounds__(256, 2)
void gemm_bt(const unsigned short* __restrict__ A,
             const unsigned short* __restrict__ Bt,
             unsigned short* __restrict__ Cbf,
             int N, int K,
             const unsigned short* __restrict__ xn, int xnStride,
             const float* __restrict__ bn,
             const float* __restrict__ zbuf,
             const float* __restrict__ hbuf,
             float* __restrict__ out)
{
    __shared__ unsigned short lA[128*32];   // 8 KB
    __shared__ unsigned short lB[128*32];   // 8 KB
    const int tid = threadIdx.x;
    const int gm = blockIdx.x * 128, gn = blockIdx.y * 128;

    const int w  = tid >> 6, l = tid & 63;
    const int wm = (w >> 1) * 64, wn = (w & 1) * 64;
    const int lr = l & 15, lk = l >> 4;     // fragment row / k-group

    f32x4 acc[4][4] = {};

    // staging: thread t loads 16B at LDS byte t*16 (+4096 for 2nd half).
    // This matches global_load_lds's wave-uniform-base + lane*16 pattern.
    const int srow = tid >> 2;              // 0..63
    const int scol = (tid & 3) * 8;         // k element offset
    const unsigned short* Ab = A  + (size_t)(gm + srow) * K + scol;
    const unsigned short* Bb = Bt + (size_t)(gn + srow) * K + scol;
    char* lAp = (char*)lA + tid * 16;
    char* lBp = (char*)lB + tid * 16;

    for (int kt = 0; kt < K; kt += 32) {
        __syncthreads();
        __builtin_amdgcn_global_load_lds(
            (const __attribute__((address_space(1))) void*)(Ab + kt),
            (__attribute__((address_space(3))) void*)lAp, 16, 0, 0);
        __builtin_amdgcn_global_load_lds(
            (const __attribute__((address_space(1))) void*)(Ab + kt + (size_t)64*K),
            (__attribute__((address_space(3))) void*)(lAp + 4096), 16, 0, 0);
        __builtin_amdgcn_global_load_lds(
            (const __attribute__((address_space(1))) void*)(Bb + kt),
            (__attribute__((address_space(3))) void*)lBp, 16, 0, 0);
        __builtin_amdgcn_global_load_lds(
            (const __attribute__((address_space(1))) void*)(Bb + kt + (size_t)64*K),
            (__attribute__((address_space(3))) void*)(lBp + 4096), 16, 0, 0);
        __syncthreads();

        short8 af[4], bfr[4];
        #pragma unroll
        for (int mi = 0; mi < 4; mi++)
            af[mi] = *(const short8*)&lA[(wm + mi*16 + lr)*32 + lk*8];
        #pragma unroll
        for (int ni = 0; ni < 4; ni++)
            bfr[ni] = *(const short8*)&lB[(wn + ni*16 + lr)*32 + lk*8];
        #pragma unroll
        for (int mi = 0; mi < 4; mi++)
            #pragma unroll
            for (int ni = 0; ni < 4; ni++)
                acc[mi][ni] = __builtin_amdgcn_mfma_f32_16x16x32_bf16(
                    af[mi], bfr[ni], acc[mi][ni], 0, 0, 0);
    }

    // C/D layout (m89/m91 verified): col = lane&15, row = (lane>>4)*4 + reg
    #pragma unroll
    for (int mi = 0; mi < 4; mi++) {
        #pragma unroll
        for (int j = 0; j < 4; j++) {
            int row = gm + wm + mi*16 + lk*4 + j;
            #pragma unroll
            for (int ni = 0; ni < 4; ni++) {
                int col = gn + wn + ni*16 + lr;
                float v = acc[mi][ni][j];
                if (EPI == 0) {
                    Cbf[(size_t)row * N + col] = f2bf(v);
                } else {
                    float pre = v + bf2f(xn[(size_t)row * xnStride + col]) + bn[col];
                    float nv  = sigmoidf_(pre);
                    float zv  = zbuf[(size_t)row * 1024 + col];
                    float hv  = hbuf[(size_t)row * 1024 + col];
                    out[(size_t)row * 1024 + col] = (1.0f - zv) * hv + zv * nv;
                }
            }
        }
    }
}

// ---------------------------------------------------------------------------
// 4. elementwise: z = sigmoid(xz+hz+bz) (f32), rh = bf16(sigmoid(xr+hr+br)*h)
// ---------------------------------------------------------------------------
__global__ void ew1(const unsigned short* __restrict__ xzrn,
                    const unsigned short* __restrict__ hzr,
                    const float* __restrict__ bz, const float* __restrict__ br,
                    const float* __restrict__ h,
                    float* __restrict__ z, unsigned short* __restrict__ rh)
{
    int i = blockIdx.x * blockDim.x + threadIdx.x;
    int r = i >> 7;            // 128 groups of 8 per row
    int c = (i & 127) * 8;
    union { uint4 v; unsigned short s[8]; } xz, xr, hz, hr, rho;
    xz.v = *(const uint4*)(xzrn + (size_t)r*3072 + c);
    xr.v = *(const uint4*)(xzrn + (size_t)r*3072 + 1024 + c);
    hz.v = *(const uint4*)(hzr  + (size_t)r*2048 + c);
    hr.v = *(const uint4*)(hzr  + (size_t)r*2048 + 1024 + c);
    float4 h0 = *(const float4*)(h + (size_t)r*1024 + c);
    float4 h1 = *(const float4*)(h + (size_t)r*1024 + c + 4);
    float hv[8]  = {h0.x,h0.y,h0.z,h0.w,h1.x,h1.y,h1.z,h1.w};
    float4 bz0 = *(const float4*)(bz + c), bz1 = *(const float4*)(bz + c + 4);
    float4 br0 = *(const float4*)(br + c), br1 = *(const float4*)(br + c + 4);
    float bzv[8] = {bz0.x,bz0.y,bz0.z,bz0.w,bz1.x,bz1.y,bz1.z,bz1.w};
    float brv[8] = {br0.x,br0.y,br0.z,br0.w,br1.x,br1.y,br1.z,br1.w};
    float zo[8];
    #pragma unroll
    for (int j = 0; j < 8; j++) {
        float zv = sigmoidf_(bf2f(xz.s[j]) + bf2f(hz.s[j]) + bzv[j]);
        zo[j] = zv;
        float rv = sigmoidf_(bf2f(xr.s[j]) + bf2f(hr.s[j]) + brv[j]);
        rho.s[j] = f2bf(rv * hv[j]);
    }
    *(float4*)(z + (size_t)r*1024 + c)     = make_float4(zo[0],zo[1],zo[2],zo[3]);
    *(float4*)(z + (size_t)r*1024 + c + 4) = make_float4(zo[4],zo[5],zo[6],zo[7]);
    *(uint4*)(rh + (size_t)r*1024 + c) = rho.v;
}

// ---------------------------------------------------------------------------
extern "C" void kernel_launch(void* const* d_in, const int* in_sizes, int n_in,
                              void* d_out, int out_size, void* d_ws, size_t ws_size,
                              hipStream_t stream)
{
    const float* x   = (const float*)d_in[0];
    const float* h   = (const float*)d_in[1];
    const float* Wiz = (const float*)d_in[2];
    const float* Uhz = (const float*)d_in[3];
    const float* bz  = (const float*)d_in[4];
    const float* Wir = (const float*)d_in[5];
    const float* Uhr = (const float*)d_in[6];
    const float* br  = (const float*)d_in[7];
    const float* Win = (const float*)d_in[8];
    const float* Uhn = (const float*)d_in[9];
    const float* bn  = (const float*)d_in[10];
    float* out = (float*)d_out;

    char* ws = (char*)d_ws;
    const size_t MB = 1024ull * 1024ull;
    unsigned short* xw   = (unsigned short*)(ws + 0);        // 16 MB
    unsigned short* hw   = (unsigned short*)(ws + 16*MB);    // 16 MB
    unsigned short* W3t  = (unsigned short*)(ws + 32*MB);    //  6 MB  [3072][1024]
    unsigned short* U2t  = (unsigned short*)(ws + 38*MB);    //  4 MB  [2048][1024]
    unsigned short* Unt  = (unsigned short*)(ws + 42*MB);    //  2 MB  [1024][1024]
    unsigned short* xzrn = (unsigned short*)(ws + 44*MB);    // 48 MB  [8192][3072]
    unsigned short* hzr  = (unsigned short*)(ws + 92*MB);    // 32 MB  [8192][2048]
    float*          zbuf = (float*)(ws + 124*MB);            // 32 MB  [8192][1024]
    unsigned short* rh   = (unsigned short*)(ws + 156*MB);   // 16 MB  -> total 172 MB

    const int B = 8192, H = 1024;

    // 1. x,h -> bf16
    conv_xh<<<dim3(2*B*H/8/256), dim3(256), 0, stream>>>(x, h, xw, hw, B*H);

    // 2. weights -> bf16 transposed
    tconv<<<dim3(32, 32, 6), dim3(256), 0, stream>>>(
        Wiz, Wir, Win, Uhz, Uhr, Uhn,
        W3t, W3t + 1024*1024, W3t + 2*1024*1024, U2t, U2t + 1024*1024, Unt);

    // 3. x @ [Wiz|Wir|Win]  -> xzrn bf16
    gemm_bt<0><<<dim3(64, 24), dim3(256), 0, stream>>>(
        xw, W3t, xzrn, 3072, 1024, nullptr, 0, nullptr, nullptr, nullptr, nullptr);

    // 4. h @ [Uhz|Uhr] -> hzr bf16
    gemm_bt<0><<<dim3(64, 16), dim3(256), 0, stream>>>(
        hw, U2t, hzr, 2048, 1024, nullptr, 0, nullptr, nullptr, nullptr, nullptr);

    // 5. z (f32), rh (bf16)
    ew1<<<dim3(B*H/8/256), dim3(256), 0, stream>>>(xzrn, hzr, bz, br, h, zbuf, rh);

    // 6. (r*h) @ Uhn with fused GRU epilogue -> out
    gemm_bt<1><<<dim3(64, 8), dim3(256), 0, stream>>>(
        rh, Unt, nullptr, 1024, 1024, xzrn + 2048, 3072, bn, zbuf, h, out);
}

// Round 4
// 293.485 us; speedup vs baseline: 1.0657x; 1.0657x over previous
//
#include <hip/hip_runtime.h>
#include <hip/hip_bf16.h>

typedef __attribute__((ext_vector_type(8))) short short8;
typedef __attribute__((ext_vector_type(4))) float f32x4;

#define DEV __device__ __forceinline__

DEV float bf2f(unsigned short u) {
    union { unsigned int i; float f; } v;
    v.i = ((unsigned int)u) << 16;
    return v.f;
}
DEV unsigned short f2bf(float f) {
    union { float f; unsigned int i; } v; v.f = f;
    unsigned int r = v.i + 0x7FFFu + ((v.i >> 16) & 1u);
    return (unsigned short)(r >> 16);
}
DEV float sigmoidf_(float x) {
    return 1.0f / (1.0f + __expf(-x));
}

// ---------------------------------------------------------------------------
// 1. fp32 -> bf16 conversion for x and h (8 elems/thread, fully coalesced)
// ---------------------------------------------------------------------------
__global__ void conv_xh(const float* __restrict__ x, const float* __restrict__ h,
                        unsigned short* __restrict__ xw, unsigned short* __restrict__ hw,
                        int n)
{
    int i = (blockIdx.x * blockDim.x + threadIdx.x) * 8;
    const float* src; unsigned short* dst; int off;
    if (i < n) { src = x; dst = xw; off = i; }
    else       { src = h; dst = hw; off = i - n; }
    float4 a = *(const float4*)(src + off);
    float4 b = *(const float4*)(src + off + 4);
    union { uint4 v; unsigned short s[8]; } o;
    o.s[0]=f2bf(a.x); o.s[1]=f2bf(a.y); o.s[2]=f2bf(a.z); o.s[3]=f2bf(a.w);
    o.s[4]=f2bf(b.x); o.s[5]=f2bf(b.y); o.s[6]=f2bf(b.z); o.s[7]=f2bf(b.w);
    *(uint4*)(dst + off) = o.v;
}

// ---------------------------------------------------------------------------
// 2. transpose + convert weights into the two fused B^T layouts:
//    B1t [2048][2048]: rows n<1024 -> z cols (Wiz|Uhz), n>=1024 -> r cols (Wir|Uhr)
//                      cols k<1024 -> x-side W,   k>=1024 -> h-side U
//    B3t [1024][2048]: k<1024 -> Win, k>=1024 -> Uhn
// ---------------------------------------------------------------------------
__global__ void tconv(const float* __restrict__ Wiz, const float* __restrict__ Uhz,
                      const float* __restrict__ Wir, const float* __restrict__ Uhr,
                      const float* __restrict__ Win, const float* __restrict__ Uhn,
                      unsigned short* __restrict__ B1t, unsigned short* __restrict__ B3t)
{
    __shared__ float lds[32][33];           // +1 pad: conflict-free transpose
    const float* src; unsigned short* dst;
    switch (blockIdx.z) {
        case 0: src=Wiz; dst=B1t;                            break;
        case 1: src=Uhz; dst=B1t + 1024;                     break;
        case 2: src=Wir; dst=B1t + (size_t)1024*2048;        break;
        case 3: src=Uhr; dst=B1t + (size_t)1024*2048 + 1024; break;
        case 4: src=Win; dst=B3t;                            break;
        default: src=Uhn; dst=B3t + 1024;                    break;
    }
    int k0 = blockIdx.x * 32, n0 = blockIdx.y * 32;
    int tx = threadIdx.x & 31, ty = threadIdx.x >> 5;   // 32 x 8
    #pragma unroll
    for (int i = 0; i < 4; i++)
        lds[ty + 8*i][tx] = src[(size_t)(k0 + ty + 8*i)*1024 + n0 + tx];
    __syncthreads();
    #pragma unroll
    for (int i = 0; i < 4; i++)
        dst[(size_t)(n0 + ty + 8*i)*2048 + k0 + tx] = f2bf(lds[tx][ty + 8*i]);
}

// ---------------------------------------------------------------------------
// 3. bf16 GEMM, m97 structure: 128x128 tile, BK=32, 4 waves (2x2),
//    each wave 64x64 = 4x4 fragments of 16x16x32 MFMA.
//    A is split: rows [M][2048] where k<1024 reads A0[row][k], k>=1024 reads
//    A1[row][k-1024] (both row-stride 1024). Bt: [N][2048].
//    EPI==1: z/r epilogue -> zbuf(f32), rh(bf16)
//    EPI==2: final epilogue -> out = (1-z)*h + z*sigmoid(acc+bn)
// ---------------------------------------------------------------------------
template<int EPI>
__global__ __launch_bounds__(256, 2)
void gemm_bt(const unsigned short* __restrict__ A0,
             const unsigned short* __restrict__ A1,
             const unsigned short* __restrict__ Bt,
             const float* __restrict__ bias0,      // bz (EPI=1) / bn (EPI=2)
             const float* __restrict__ bias1,      // br (EPI=1) / unused
             const float* __restrict__ hsrc,       // h (f32)
             float* __restrict__ zbuf,             // EPI=1: out z; EPI=2: in z
             unsigned short* __restrict__ rh,      // EPI=1 out
             float* __restrict__ out)              // EPI=2 out
{
    __shared__ unsigned short lA[128*32];   // 8 KB
    __shared__ unsigned short lB[128*32];   // 8 KB
    const int tid = threadIdx.x;
    const int gm = blockIdx.x * 128, gn = blockIdx.y * 128;

    const int w  = tid >> 6, l = tid & 63;
    const int wm = (w >> 1) * 64, wn = (w & 1) * 64;
    const int lr = l & 15, lk = l >> 4;     // fragment row / k-group

    f32x4 acc[4][4] = {};

    const int srow = tid >> 2;              // 0..63
    const int scol = (tid & 3) * 8;         // k element offset
    char* lAp = (char*)lA + tid * 16;
    char* lBp = (char*)lB + tid * 16;

    for (int kt = 0; kt < 2048; kt += 32) {
        const unsigned short* Ab = (kt < 1024 ? A0 : A1)
                                 + (size_t)(gm + srow) * 1024 + (kt & 1023) + scol;
        const unsigned short* Bb = Bt + (size_t)(gn + srow) * 2048 + kt + scol;
        __syncthreads();
        __builtin_amdgcn_global_load_lds(
            (const __attribute__((address_space(1))) void*)Ab,
            (__attribute__((address_space(3))) void*)lAp, 16, 0, 0);
        __builtin_amdgcn_global_load_lds(
            (const __attribute__((address_space(1))) void*)(Ab + (size_t)64*1024),
            (__attribute__((address_space(3))) void*)(lAp + 4096), 16, 0, 0);
        __builtin_amdgcn_global_load_lds(
            (const __attribute__((address_space(1))) void*)Bb,
            (__attribute__((address_space(3))) void*)lBp, 16, 0, 0);
        __builtin_amdgcn_global_load_lds(
            (const __attribute__((address_space(1))) void*)(Bb + (size_t)64*2048),
            (__attribute__((address_space(3))) void*)(lBp + 4096), 16, 0, 0);
        __syncthreads();

        short8 af[4], bfr[4];
        #pragma unroll
        for (int mi = 0; mi < 4; mi++)
            af[mi] = *(const short8*)&lA[(wm + mi*16 + lr)*32 + lk*8];
        #pragma unroll
        for (int ni = 0; ni < 4; ni++)
            bfr[ni] = *(const short8*)&lB[(wn + ni*16 + lr)*32 + lk*8];
        #pragma unroll
        for (int mi = 0; mi < 4; mi++)
            #pragma unroll
            for (int ni = 0; ni < 4; ni++)
                acc[mi][ni] = __builtin_amdgcn_mfma_f32_16x16x32_bf16(
                    af[mi], bfr[ni], acc[mi][ni], 0, 0, 0);
    }

    // C/D layout (m89/m91 verified): col = lane&15, row = (lane>>4)*4 + reg
    #pragma unroll
    for (int mi = 0; mi < 4; mi++) {
        #pragma unroll
        for (int j = 0; j < 4; j++) {
            int row = gm + wm + mi*16 + lk*4 + j;
            #pragma unroll
            for (int ni = 0; ni < 4; ni++) {
                int col = gn + wn + ni*16 + lr;
                float v = acc[mi][ni][j];
                if (EPI == 1) {
                    if (col < 1024) {
                        zbuf[(size_t)row*1024 + col] = sigmoidf_(v + bias0[col]);
                    } else {
                        int c = col - 1024;
                        float rv = sigmoidf_(v + bias1[c]);
                        rh[(size_t)row*1024 + c] =
                            f2bf(rv * hsrc[(size_t)row*1024 + c]);
                    }
                } else {
                    float nv = sigmoidf_(v + bias0[col]);
                    float zv = zbuf[(size_t)row*1024 + col];
                    float hv = hsrc[(size_t)row*1024 + col];
                    out[(size_t)row*1024 + col] = (1.0f - zv)*hv + zv*nv;
                }
            }
        }
    }
}

// ---------------------------------------------------------------------------
extern "C" void kernel_launch(void* const* d_in, const int* in_sizes, int n_in,
                              void* d_out, int out_size, void* d_ws, size_t ws_size,
                              hipStream_t stream)
{
    const float* x   = (const float*)d_in[0];
    const float* h   = (const float*)d_in[1];
    const float* Wiz = (const float*)d_in[2];
    const float* Uhz = (const float*)d_in[3];
    const float* bz  = (const float*)d_in[4];
    const float* Wir = (const float*)d_in[5];
    const float* Uhr = (const float*)d_in[6];
    const float* br  = (const float*)d_in[7];
    const float* Win = (const float*)d_in[8];
    const float* Uhn = (const float*)d_in[9];
    const float* bn  = (const float*)d_in[10];
    float* out = (float*)d_out;

    char* ws = (char*)d_ws;
    const size_t MB = 1024ull * 1024ull;
    unsigned short* xw   = (unsigned short*)(ws + 0);        // 16 MB [8192][1024]
    unsigned short* hw   = (unsigned short*)(ws + 16*MB);    // 16 MB [8192][1024]
    unsigned short* B1t  = (unsigned short*)(ws + 32*MB);    //  8 MB [2048][2048]
    unsigned short* B3t  = (unsigned short*)(ws + 40*MB);    //  4 MB [1024][2048]
    float*          zbuf = (float*)(ws + 44*MB);             // 32 MB [8192][1024]
    unsigned short* rh   = (unsigned short*)(ws + 76*MB);    // 16 MB -> total 92 MB

    const int B = 8192, H = 1024;

    // 1. x,h -> bf16
    conv_xh<<<dim3(2*B*H/8/256), dim3(256), 0, stream>>>(x, h, xw, hw, B*H);

    // 2. weights -> fused bf16 B^T layouts
    tconv<<<dim3(32, 32, 6), dim3(256), 0, stream>>>(
        Wiz, Uhz, Wir, Uhr, Win, Uhn, B1t, B3t);

    // 3. [x|h] @ [[Wiz|Wir],[Uhz|Uhr]] with fused z/r epilogue
    gemm_bt<1><<<dim3(64, 16), dim3(256), 0, stream>>>(
        xw, hw, B1t, bz, br, h, zbuf, rh, nullptr);

    // 4. [x|rh] @ [[Win],[Uhn]] with fused GRU output epilogue
    gemm_bt<2><<<dim3(64, 8), dim3(256), 0, stream>>>(
        xw, rh, B3t, bn, nullptr, h, zbuf, nullptr, out);
}